// Round 5
// baseline (173.298 us; speedup 1.0000x reference)
//
#include <hip/hip_runtime.h>
#include <hip/hip_bf16.h>

// ---- problem constants ----
#define T_DIM   2048
#define A_DIM   64
#define N_TOK   (T_DIM * A_DIM)     // 131072
#define RAWOB   120
#define N_TP    5
#define E_EXP   10
#define D_DIM   126                  // RAWOB + N_TP + 1
#define DP      128                  // padded K (row 126 = bias, row 127 = 0)
#define H_DIM   128
#define N_ACT   16
#define CAP     14336                // per-expert capacity (mean 13107, +11 sigma)
#define BTOK    256                  // tokens per block (8 waves x 32)
#define MAXC    (CAP / BTOK)         // 56 chunks per expert
#define LOGITS_SZ (N_TOK * N_ACT)    // 2097152

typedef __bf16 bh8 __attribute__((ext_vector_type(8)));
typedef ushort u16x8 __attribute__((ext_vector_type(8)));
typedef ushort u16x4 __attribute__((ext_vector_type(4)));
typedef short  s16x4 __attribute__((ext_vector_type(4)));
typedef float  f32x4 __attribute__((ext_vector_type(4)));

__device__ __forceinline__ f32x4 mfma16(bh8 a, bh8 b, f32x4 c) {
    return __builtin_amdgcn_mfma_f32_16x16x32_bf16(a, b, c, 0, 0, 0);
}
// K=16 variant: per-lane k-quads (k = 4*lq + j) — matches swapped-L1 output layout
__device__ __forceinline__ f32x4 mfma16k16(s16x4 a, s16x4 b, f32x4 c) {
    return __builtin_amdgcn_mfma_f32_16x16x16bf16_1k(a, b, c, 0, 0, 0);
}

__device__ __forceinline__ ushort f2bf(float f) {
    unsigned x = __builtin_bit_cast(unsigned, f);
    unsigned r = (x + 0x7fffu + ((x >> 16) & 1u)) >> 16;   // round-nearest-even
    return (ushort)r;
}

#define W1P_N (E_EXP * H_DIM * DP)           // 163840 ushorts
#define W2P_N (E_EXP * N_ACT * H_DIM)        // 20480
#define WC1P_N (DP * DP)                     // 16384
#define XG_N  (E_EXP * CAP * 128)            // 18350080 ushorts (36.7 MB)

// moe LDS layout (ushort offsets): W1e @0 (16384), W2e @16384 (2048)
#define LDS_W2  16384
#define LDS_TOT 18432                        // 36864 B

// ---------------- kernel 0: prep (pack + bucket + GATHER) ----------------
// blocks 0..43:   W1/Wc1 packing (bias folded into padded row 126)
// blocks 44..123: W2 packing (16x16x16 B-frag layout)
// blocks 124..635: bucket + gather: 256 tokens/block. Each token's augmented
//   row is converted to bf16 ONCE and written to xg[e*CAP+pos] (256B, contiguous)
//   with bias-1.0 at slot 126 and 0 at slot 127. moe then reads xg linearly.
#define PB_BLOCKS 636

__global__ __launch_bounds__(256) void prep_bucket_kernel(
    const float* __restrict__ W1, const float* __restrict__ W2,
    const float* __restrict__ Wc1, const float* __restrict__ b1,
    const float* __restrict__ bc1, const int* __restrict__ pick,
    const float* __restrict__ obs, const int* __restrict__ hete_type,
    const int* __restrict__ gp_sel,
    int* __restrict__ counts, int* __restrict__ order,
    ushort* __restrict__ W1p, ushort* __restrict__ W2p, ushort* __restrict__ Wc1p,
    ushort* __restrict__ xg)
{
    int bx = blockIdx.x, tid = threadIdx.x;
    if (bx < 44) {
        __shared__ ushort st[32][130];   // 32 d-rows x 128 n, padded
        const float* src;
        const float* bias;
        ushort* dstbase;
        int kt;
        if (bx < 40) {                   // W1: e = bx>>2, kt = bx&3
            int e = bx >> 2;
            kt = bx & 3;
            src = W1 + (e * D_DIM + kt * 32) * H_DIM;
            bias = b1 + e * H_DIM;
            dstbase = W1p + e * (H_DIM * DP);
        } else {                         // Wc1: kt = bx-40
            kt = bx - 40;
            src = Wc1 + kt * 32 * H_DIM;
            bias = bc1;
            dstbase = Wc1p;
        }
        int dmax = D_DIM - kt * 32;      // 32,32,32,30
#pragma unroll
        for (int p = 0; p < 16; ++p) {
            int idx = p * 256 + tid;
            int dd = idx >> 7, n = idx & 127;
            float v;
            if (dd < dmax)                    v = src[dd * H_DIM + n];   // coalesced in n
            else if (kt == 3 && dd == 30)     v = bias[n];               // bias row (k=126)
            else                              v = 0.f;                   // k=127 pad
            st[dd][n] = f2bf(v);
        }
        __syncthreads();
#pragma unroll
        for (int p = 0; p < 16; ++p) {
            int idx = p * 256 + tid;
            int dd = idx >> 7, n = idx & 127;
            // frag position: nt=n>>4, lm=n&15, lq=dd>>3, j=dd&7
            dstbase[((n >> 4) * 4 + kt) * 512 + ((dd >> 3) * 16 + (n & 15)) * 8 + (dd & 7)]
                = st[dd][n];
        }
    } else if (bx < 124) {
        // W2 packed as 16x16x16 B-frags: tile kk (k = kk*16 + 4*lq + j), col = lm
        int i = (bx - 44) * 256 + tid;   // [0, 20480)
        int e   = i >> 11;
        int rem = i & 2047;
        int kk  = rem >> 8;
        int idx = rem & 255;
        int l = idx >> 2, j = idx & 3;
        int lq = l >> 4, lm = l & 15;
        W2p[i] = f2bf(W2[(e * H_DIM + kk * 16 + lq * 4 + j) * N_ACT + lm]);
    } else {
        // ---- bucket + gather: 256 tokens/block, one token per thread ----
        __shared__ int lc[E_EXP], lb[E_EXP];
        __shared__ int stok[256], sslot[256];
        const int tok = (bx - 124) * 256 + tid;
        if (tid < E_EXP) lc[tid] = 0;
        __syncthreads();
        const int e = pick[tok];
        const int loc = atomicAdd(&lc[e], 1);       // dense rank within block
        __syncthreads();
        if (tid < E_EXP) lb[tid] = atomicAdd(&counts[tid * 16], lc[tid]);
        __syncthreads();
        const int pos = lb[e] + loc;
        int s = -1;
        if (pos < CAP) {
            s = e * CAP + pos;
            order[s] = tok;                         // token id by slot (for moe scatter)
        }
        stok[tid] = tok;
        sslot[tid] = s;
        __syncthreads();
        // ---- gather: 16 lanes per token row (coalesced read, contiguous write) ----
        const int chunk = tid & 15;                 // 16B chunk within the row
#pragma unroll 4
        for (int p = 0; p < 16; ++p) {
            const int ti = p * 16 + (tid >> 4);     // token index within block
            const int ss = sslot[ti];
            if (ss < 0) continue;
            const int tk = stok[ti];
            ushort* dst = xg + (size_t)ss * 128 + chunk * 8;
            u16x8 t;
            if (chunk < 15) {                       // k = chunk*8 .. +7 from obs
                const float* p0 = obs + tk * RAWOB + chunk * 8;
                float4 u0 = *(const float4*)(const void*)p0;
                float4 u1 = *(const float4*)(const void*)(p0 + 4);
                t[0] = f2bf(u0.x); t[1] = f2bf(u0.y); t[2] = f2bf(u0.z); t[3] = f2bf(u0.w);
                t[4] = f2bf(u1.x); t[5] = f2bf(u1.y); t[6] = f2bf(u1.z); t[7] = f2bf(u1.w);
            } else {                                // k = 120..127: augment
                int ht = hete_type[tk];
                int tt = tk >> 6;                   // token / A_DIM
                t[0] = f2bf((float)ht);
#pragma unroll
                for (int q = 0; q < N_TP; ++q) {
                    float g = (q == ht) ? -1.0f : (float)gp_sel[tt * N_TP + q];
                    t[1 + q] = f2bf(g);
                }
                t[6] = (ushort)0x3F80;              // 1.0 -> picks up bias row 126
                t[7] = 0;
            }
            *(u16x8*)(void*)dst = t;
        }
    }
}

// ---------------- kernel 1: fused expert + critic, xg-fed ------------------
// 512 threads = 8 waves x 32 tokens. A-frags come from xg: linear, bf16, zero
// conversion, zero gather on the critical path (order only gates the stores).
// LDS 36KB = W1e+W2e -> one barrier; critic reads Wc1p from L2 (32KB chip-hot).
__global__ __launch_bounds__(512, 6) void moe_kernel(
    const ushort* __restrict__ xg,
    const float* __restrict__ b2, const float* __restrict__ bc2,
    const int* __restrict__ order,
    const ushort* __restrict__ W1p, const ushort* __restrict__ W2p,
    const ushort* __restrict__ Wc1p, const float* __restrict__ Wc2,
    float* __restrict__ out)
{
    __shared__ __align__(16) ushort wlds[LDS_TOT];

    const int bx = blockIdx.x;
    const int e = bx % E_EXP;
    const int c = bx / E_EXP;
    const int start = c * BTOK;
    const int* ord_e = order + e * CAP;
    if (ord_e[start] < 0) return;               // whole chunk beyond cnt (uniform)

    const int tid = threadIdx.x;
    const int w = tid >> 6;
    const int base = start + w * 32;            // this wave's token-slot offset
    const int l = tid & 63;
    const int lm = l & 15;
    const int lq = l >> 4;

    // ---- per-lane store targets (only needed at the stores; off critical path) --
    int sraw[2];
    sraw[0] = ord_e[base + lm];
    sraw[1] = ord_e[base + 16 + lm];

    // ---- stage W1e (32KB) + W2e (4KB) packed frags into LDS (512 threads) ----
    {
        const u16x8* s1 = (const u16x8*)(const void*)(W1p + e * (H_DIM * DP));
        u16x8* d1 = (u16x8*)(void*)wlds;
#pragma unroll
        for (int p = 0; p < 4; ++p) d1[p * 512 + tid] = s1[p * 512 + tid];
        if (tid < 256)
            ((u16x8*)(void*)(wlds + LDS_W2))[tid] =
                ((const u16x8*)(const void*)(W2p + e * 2048))[tid];
    }

    // ---- A-fragments straight from xg: 4 x b128 per m-frag, coalesced ----
    const ushort* xbase = xg + (size_t)(e * CAP + base) * 128;
    bh8 a[2][4];
#pragma unroll
    for (int mt = 0; mt < 2; ++mt)
#pragma unroll
        for (int kt = 0; kt < 4; ++kt)
            a[mt][kt] = *(const bh8*)(const void*)
                        (xbase + (mt * 16 + lm) * 128 + kt * 32 + lq * 8);

    const float bb  = b2[e * N_ACT + lm];
    const float bcv = bc2[0];

    __syncthreads();   // W1e/W2e staged (only barrier in the kernel)

    // ---- expert path: swapped L1 (h^T in regs) -> ReLU/pack -> 16x16x16 L2 ----
    // nt-outer: each W1/W2 LDS fragment read ONCE, feeds both m-frags.
    {
        f32x4 y0 = (f32x4){0.f, 0.f, 0.f, 0.f};
        f32x4 y1 = (f32x4){0.f, 0.f, 0.f, 0.f};
#pragma unroll
        for (int nt = 0; nt < 8; ++nt) {
            f32x4 ae0 = (f32x4){0.f, 0.f, 0.f, 0.f}, ae1 = ae0;
#pragma unroll
            for (int kt = 0; kt < 4; ++kt) {
                bh8 wf = *(const bh8*)(const void*)(wlds + (nt * 4 + kt) * 512 + l * 8);
                ae0 = mfma16(wf, a[0][kt], ae0);        // swapped operands
                ae1 = mfma16(wf, a[1][kt], ae1);
            }
            u16x4 hp0, hp1;
#pragma unroll
            for (int r = 0; r < 4; ++r) {
                hp0[r] = f2bf(fmaxf(ae0[r], 0.f));
                hp1[r] = f2bf(fmaxf(ae1[r], 0.f));
            }
            s16x4 w2f = *(const s16x4*)(const void*)(wlds + LDS_W2 + nt * 256 + l * 4);
            y0 = mfma16k16(__builtin_bit_cast(s16x4, hp0), w2f, y0);
            y1 = mfma16k16(__builtin_bit_cast(s16x4, hp1), w2f, y1);
        }
#pragma unroll
        for (int r = 0; r < 4; ++r) {
            int s0 = ord_e[base + lq * 4 + r];
            if (s0 >= 0) out[s0 * N_ACT + lm] = y0[r] + bb;
            int s1 = ord_e[base + 16 + lq * 4 + r];
            if (s1 >= 0) out[s1 * N_ACT + lm] = y1[r] + bb;
        }
    }

    // ---- critic: swapped L1 with Wc1 frags from L2 (32KB, chip-hot) ----
    {
        float p0 = 0.f, p1 = 0.f;
#pragma unroll
        for (int nt = 0; nt < 8; ++nt) {
            f32x4 c0 = (f32x4){0.f,0.f,0.f,0.f}, c1 = c0;
#pragma unroll
            for (int kt = 0; kt < 4; ++kt) {
                bh8 wf = *(const bh8*)(const void*)(Wc1p + (nt * 4 + kt) * 512 + l * 8);
                c0 = mfma16(wf, a[0][kt], c0);
                c1 = mfma16(wf, a[1][kt], c1);
            }
            const float4 wc = *(const float4*)(const void*)(Wc2 + nt * 16 + lq * 4);
            p0 += fmaxf(c0[0], 0.f) * wc.x + fmaxf(c0[1], 0.f) * wc.y
                + fmaxf(c0[2], 0.f) * wc.z + fmaxf(c0[3], 0.f) * wc.w;
            p1 += fmaxf(c1[0], 0.f) * wc.x + fmaxf(c1[1], 0.f) * wc.y
                + fmaxf(c1[2], 0.f) * wc.z + fmaxf(c1[3], 0.f) * wc.w;
        }
        // lane (lq,lm) holds token lm's partial over its n-subset; sum over lq
        p0 += __shfl_xor(p0, 16, 64); p0 += __shfl_xor(p0, 32, 64);
        p1 += __shfl_xor(p1, 16, 64); p1 += __shfl_xor(p1, 32, 64);
        if (lq == 0) {
            if (sraw[0] >= 0) out[LOGITS_SZ + sraw[0]] = p0 + bcv;
            if (sraw[1] >= 0) out[LOGITS_SZ + sraw[1]] = p1 + bcv;
        }
    }
}

extern "C" void kernel_launch(void* const* d_in, const int* in_sizes, int n_in,
                              void* d_out, int out_size, void* d_ws, size_t ws_size,
                              hipStream_t stream) {
    const float* obs  = (const float*)d_in[0];
    const int*   pick = (const int*)d_in[1];
    const int*   htyp = (const int*)d_in[2];
    const int*   gp   = (const int*)d_in[3];
    const float* W1   = (const float*)d_in[4];
    const float* b1   = (const float*)d_in[5];
    const float* W2   = (const float*)d_in[6];
    const float* b2   = (const float*)d_in[7];
    const float* Wc1  = (const float*)d_in[8];
    const float* bc1  = (const float*)d_in[9];
    const float* Wc2  = (const float*)d_in[10];
    const float* bc2  = (const float*)d_in[11];
    float* out = (float*)d_out;

    int*    counts = (int*)d_ws;              // 160 ints (padded, e -> counts[e*16])
    int*    order  = counts + 160;            // E_EXP * CAP ints (-1 sentinel)
    ushort* W1p    = (ushort*)(order + E_EXP * CAP);
    ushort* W2p    = W1p + W1P_N;
    ushort* Wc1p   = W2p + W2P_N;
    ushort* xg     = Wc1p + WC1P_N;           // E_EXP*CAP*128 ushorts (36.7 MB)

    hipMemsetAsync(counts, 0, 160 * sizeof(int), stream);
    hipMemsetAsync(order, 0xFF, E_EXP * CAP * sizeof(int), stream);
    prep_bucket_kernel<<<PB_BLOCKS, 256, 0, stream>>>(
        W1, W2, Wc1, b1, bc1, pick, obs, htyp, gp,
        counts, order, W1p, W2p, Wc1p, xg);
    moe_kernel<<<E_EXP * MAXC, 512, 0, stream>>>(
        xg, b2, bc2, order, W1p, W2p, Wc1p, Wc2, out);
}

// Round 6
// 168.844 us; speedup vs baseline: 1.0264x; 1.0264x over previous
//
#include <hip/hip_runtime.h>
#include <hip/hip_bf16.h>

// ---- problem constants ----
#define T_DIM   2048
#define A_DIM   64
#define N_TOK   (T_DIM * A_DIM)     // 131072
#define RAWOB   120
#define N_TP    5
#define E_EXP   10
#define D_DIM   126                  // RAWOB + N_TP + 1
#define DP      128                  // padded K (row 126 = bias, row 127 = 0)
#define H_DIM   128
#define N_ACT   16
#define CAP     14336                // per-expert capacity (mean 13107, +11 sigma)
#define BTOK    256                  // tokens per block (8 waves x 32)
#define MAXC    (CAP / BTOK)         // 56 chunks per expert
#define LOGITS_SZ (N_TOK * N_ACT)    // 2097152

typedef __bf16 bh8 __attribute__((ext_vector_type(8)));
typedef ushort u16x8 __attribute__((ext_vector_type(8)));
typedef ushort u16x4 __attribute__((ext_vector_type(4)));
typedef short  s16x4 __attribute__((ext_vector_type(4)));
typedef float  f32x4 __attribute__((ext_vector_type(4)));

__device__ __forceinline__ f32x4 mfma16(bh8 a, bh8 b, f32x4 c) {
    return __builtin_amdgcn_mfma_f32_16x16x32_bf16(a, b, c, 0, 0, 0);
}
// K=16 variant: per-lane k-quads (k = 4*lq + j) — matches swapped-L1 output layout
__device__ __forceinline__ f32x4 mfma16k16(s16x4 a, s16x4 b, f32x4 c) {
    return __builtin_amdgcn_mfma_f32_16x16x16bf16_1k(a, b, c, 0, 0, 0);
}

__device__ __forceinline__ ushort f2bf(float f) {
    unsigned x = __builtin_bit_cast(unsigned, f);
    unsigned r = (x + 0x7fffu + ((x >> 16) & 1u)) >> 16;   // round-nearest-even
    return (ushort)r;
}

#define W1P_N (E_EXP * H_DIM * DP)           // 163840 ushorts
#define W2P_N (E_EXP * N_ACT * H_DIM)        // 20480
#define WC1P_N (DP * DP)                     // 16384

// moe LDS layout (ushort offsets): W1e @0 (16384), W2e @16384 (2048)
#define LDS_W2  16384
#define LDS_TOT 18432                        // 36864 B -> 4 blocks/CU

// ---------------- kernel 0: merged prep (fragment packing) + bucket ----------------
// blocks 0..43:   W1/Wc1 packing (bias folded into padded row 126)
// blocks 44..123: W2 packing (16x16x16 B-frag layout)
// blocks 124..155: token bucketing, 4096 tokens/block (counts zeroed, order
//                  pre-filled with -1 sentinel via hipMemsetAsync)
#define PB_BLOCKS 156

__global__ __launch_bounds__(256) void prep_bucket_kernel(
    const float* __restrict__ W1, const float* __restrict__ W2,
    const float* __restrict__ Wc1, const float* __restrict__ b1,
    const float* __restrict__ bc1, const int* __restrict__ pick,
    int* __restrict__ counts, int* __restrict__ order,
    ushort* __restrict__ W1p, ushort* __restrict__ W2p, ushort* __restrict__ Wc1p)
{
    int bx = blockIdx.x, tid = threadIdx.x;
    if (bx < 44) {
        __shared__ ushort st[32][130];   // 32 d-rows x 128 n, padded
        const float* src;
        const float* bias;
        ushort* dstbase;
        int kt;
        if (bx < 40) {                   // W1: e = bx>>2, kt = bx&3
            int e = bx >> 2;
            kt = bx & 3;
            src = W1 + (e * D_DIM + kt * 32) * H_DIM;
            bias = b1 + e * H_DIM;
            dstbase = W1p + e * (H_DIM * DP);
        } else {                         // Wc1: kt = bx-40
            kt = bx - 40;
            src = Wc1 + kt * 32 * H_DIM;
            bias = bc1;
            dstbase = Wc1p;
        }
        int dmax = D_DIM - kt * 32;      // 32,32,32,30
#pragma unroll
        for (int p = 0; p < 16; ++p) {
            int idx = p * 256 + tid;
            int dd = idx >> 7, n = idx & 127;
            float v;
            if (dd < dmax)                    v = src[dd * H_DIM + n];   // coalesced in n
            else if (kt == 3 && dd == 30)     v = bias[n];               // bias row (k=126)
            else                              v = 0.f;                   // k=127 pad
            st[dd][n] = f2bf(v);
        }
        __syncthreads();
#pragma unroll
        for (int p = 0; p < 16; ++p) {
            int idx = p * 256 + tid;
            int dd = idx >> 7, n = idx & 127;
            // frag position: nt=n>>4, lm=n&15, lq=dd>>3, j=dd&7
            dstbase[((n >> 4) * 4 + kt) * 512 + ((dd >> 3) * 16 + (n & 15)) * 8 + (dd & 7)]
                = st[dd][n];
        }
    } else if (bx < 124) {
        // W2 packed as 16x16x16 B-frags: tile kk (k = kk*16 + 4*lq + j), col = lm
        int i = (bx - 44) * 256 + tid;   // [0, 20480)
        int e   = i >> 11;
        int rem = i & 2047;
        int kk  = rem >> 8;
        int idx = rem & 255;
        int l = idx >> 2, j = idx & 3;
        int lq = l >> 4, lm = l & 15;
        W2p[i] = f2bf(W2[(e * H_DIM + kk * 16 + lq * 4 + j) * N_ACT + lm]);
    } else {
        // ---- bucket: 4096 tokens/block; rank from counting atomic directly ----
        __shared__ int lc[E_EXP], lb[E_EXP];
        if (tid < E_EXP) lc[tid] = 0;
        __syncthreads();
        int base = (bx - 124) * 4096;
        int ev[16], loc[16];
#pragma unroll
        for (int it = 0; it < 16; ++it) {
            ev[it] = pick[base + it * 256 + tid];
            loc[it] = atomicAdd(&lc[ev[it]], 1);    // unique rank within block
        }
        __syncthreads();
        if (tid < E_EXP) lb[tid] = atomicAdd(&counts[tid * 16], lc[tid]);
        __syncthreads();
#pragma unroll
        for (int it = 0; it < 16; ++it) {
            int e = ev[it];
            int pos = lb[e] + loc[it];
            if (pos < CAP) order[e * CAP + pos] = base + it * 256 + tid;
        }
    }
}

// ---------------- kernel 1: LDS-staged-weights fused expert + critic ------------
// 512 threads = 8 waves x 32 tokens, 2 m-frags/wave (W1/W2 LDS frags shared
// across both). LDS = 36KB (W1e+W2e) and launch_bounds(512,8) pins VGPR<=64 ->
// 4 blocks/CU x 8 waves = 32 waves/CU: 2x R4's occupancy to hide the scattered
// obs gather. Critic reads Wc1p (32KB, chip-hot) straight from L2. One barrier.
__global__ __launch_bounds__(512, 8) void moe_kernel(
    const float* __restrict__ obs, const int* __restrict__ hete_type,
    const int* __restrict__ gp_sel,
    const float* __restrict__ b2, const float* __restrict__ bc2,
    const int* __restrict__ order,
    const ushort* __restrict__ W1p, const ushort* __restrict__ W2p,
    const ushort* __restrict__ Wc1p, const float* __restrict__ Wc2,
    float* __restrict__ out)
{
    __shared__ __align__(16) ushort wlds[LDS_TOT];

    const int bx = blockIdx.x;
    const int e = bx % E_EXP;
    const int c = bx / E_EXP;
    const int start = c * BTOK;
    const int* ord_e = order + e * CAP;
    if (ord_e[start] < 0) return;               // whole chunk beyond cnt (uniform)

    const int tid = threadIdx.x;
    const int w = tid >> 6;
    const int base = start + w * 32;            // this wave's token-slot offset
    const int l = tid & 63;
    const int lm = l & 15;
    const int lq = l >> 4;

    // ---- issue this lane's order reads FIRST (the head of the miss chain) ----
    int sraw[2];
    sraw[0] = ord_e[base + lm];
    sraw[1] = ord_e[base + 16 + lm];

    // ---- stage W1e (32KB) + W2e (4KB) packed frags into LDS (512 threads) ----
    // independent of the order reads -> fills their miss shadow
    {
        const u16x8* s1 = (const u16x8*)(const void*)(W1p + e * (H_DIM * DP));
        u16x8* d1 = (u16x8*)(void*)wlds;
#pragma unroll
        for (int p = 0; p < 4; ++p) d1[p * 512 + tid] = s1[p * 512 + tid];
        if (tid < 256)
            ((u16x8*)(void*)(wlds + LDS_W2))[tid] =
                ((const u16x8*)(const void*)(W2p + e * 2048))[tid];
    }

    // ---- build A-fragments for 2 m-tiles directly from obs (+augment) ----
    // lane l holds x[token = base+mt*16+lm][k = kt*32 + lq*8 + j]; k=126 slot = 1.0
    bh8 a[2][4];
#pragma unroll
    for (int mt = 0; mt < 2; ++mt) {
        const int tok = sraw[mt] < 0 ? 0 : sraw[mt];    // sentinel -> dummy row 0
        const float* orow = obs + tok * RAWOB;
#pragma unroll
        for (int kt = 0; kt < 3; ++kt) {
            const float* p = orow + kt * 32 + lq * 8;
            float4 u0 = *(const float4*)(const void*)p;
            float4 u1 = *(const float4*)(const void*)(p + 4);
            u16x8 t;
            t[0] = f2bf(u0.x); t[1] = f2bf(u0.y); t[2] = f2bf(u0.z); t[3] = f2bf(u0.w);
            t[4] = f2bf(u1.x); t[5] = f2bf(u1.y); t[6] = f2bf(u1.z); t[7] = f2bf(u1.w);
            a[mt][kt] = __builtin_bit_cast(bh8, t);
        }
        u16x8 t;
        if (lq < 3) {   // k = 96..119 from obs
            const float* p = orow + 96 + lq * 8;
            float4 u0 = *(const float4*)(const void*)p;
            float4 u1 = *(const float4*)(const void*)(p + 4);
            t[0] = f2bf(u0.x); t[1] = f2bf(u0.y); t[2] = f2bf(u0.z); t[3] = f2bf(u0.w);
            t[4] = f2bf(u1.x); t[5] = f2bf(u1.y); t[6] = f2bf(u1.z); t[7] = f2bf(u1.w);
        } else {        // k = 120..127: [hete_type, gp_obs(5), 1.0 (bias), 0]
            int ht = hete_type[tok];
            int tt = tok >> 6;                  // token / A_DIM
            t[0] = f2bf((float)ht);
#pragma unroll
            for (int q = 0; q < N_TP; ++q) {
                float g = (q == ht) ? -1.0f : (float)gp_sel[tt * N_TP + q];
                t[1 + q] = f2bf(g);
            }
            t[6] = (ushort)0x3F80;              // 1.0 -> picks up bias row 126
            t[7] = 0;
        }
        a[mt][3] = __builtin_bit_cast(bh8, t);
    }

    const float bb  = b2[e * N_ACT + lm];
    const float bcv = bc2[0];

    __syncthreads();   // W1e/W2e staged (only barrier in the kernel)

    // ---- expert path: swapped L1 (h^T in regs) -> ReLU/pack -> 16x16x16 L2 ----
    // nt-outer: each W1/W2 LDS fragment read ONCE, feeds both m-frags.
    {
        f32x4 y0 = (f32x4){0.f, 0.f, 0.f, 0.f};
        f32x4 y1 = (f32x4){0.f, 0.f, 0.f, 0.f};
#pragma unroll
        for (int nt = 0; nt < 8; ++nt) {
            f32x4 ae0 = (f32x4){0.f, 0.f, 0.f, 0.f}, ae1 = ae0;
#pragma unroll
            for (int kt = 0; kt < 4; ++kt) {
                bh8 wf = *(const bh8*)(const void*)(wlds + (nt * 4 + kt) * 512 + l * 8);
                ae0 = mfma16(wf, a[0][kt], ae0);        // swapped operands
                ae1 = mfma16(wf, a[1][kt], ae1);
            }
            u16x4 hp0, hp1;
#pragma unroll
            for (int r = 0; r < 4; ++r) {
                hp0[r] = f2bf(fmaxf(ae0[r], 0.f));
                hp1[r] = f2bf(fmaxf(ae1[r], 0.f));
            }
            s16x4 w2f = *(const s16x4*)(const void*)(wlds + LDS_W2 + nt * 256 + l * 4);
            y0 = mfma16k16(__builtin_bit_cast(s16x4, hp0), w2f, y0);
            y1 = mfma16k16(__builtin_bit_cast(s16x4, hp1), w2f, y1);
        }
#pragma unroll
        for (int r = 0; r < 4; ++r) {
            int s0 = ord_e[base + lq * 4 + r];
            if (s0 >= 0) out[s0 * N_ACT + lm] = y0[r] + bb;
            int s1 = ord_e[base + 16 + lq * 4 + r];
            if (s1 >= 0) out[s1 * N_ACT + lm] = y1[r] + bb;
        }
    }

    // ---- critic: swapped L1 with Wc1 frags from L2 (32KB, chip-hot) ----
    {
        float p0 = 0.f, p1 = 0.f;
#pragma unroll
        for (int nt = 0; nt < 8; ++nt) {
            f32x4 c0 = (f32x4){0.f,0.f,0.f,0.f}, c1 = c0;
#pragma unroll
            for (int kt = 0; kt < 4; ++kt) {
                bh8 wf = *(const bh8*)(const void*)(Wc1p + (nt * 4 + kt) * 512 + l * 8);
                c0 = mfma16(wf, a[0][kt], c0);
                c1 = mfma16(wf, a[1][kt], c1);
            }
            const float4 wc = *(const float4*)(const void*)(Wc2 + nt * 16 + lq * 4);
            p0 += fmaxf(c0[0], 0.f) * wc.x + fmaxf(c0[1], 0.f) * wc.y
                + fmaxf(c0[2], 0.f) * wc.z + fmaxf(c0[3], 0.f) * wc.w;
            p1 += fmaxf(c1[0], 0.f) * wc.x + fmaxf(c1[1], 0.f) * wc.y
                + fmaxf(c1[2], 0.f) * wc.z + fmaxf(c1[3], 0.f) * wc.w;
        }
        // lane (lq,lm) holds token lm's partial over its n-subset; sum over lq
        p0 += __shfl_xor(p0, 16, 64); p0 += __shfl_xor(p0, 32, 64);
        p1 += __shfl_xor(p1, 16, 64); p1 += __shfl_xor(p1, 32, 64);
        if (lq == 0) {
            if (sraw[0] >= 0) out[LOGITS_SZ + sraw[0]] = p0 + bcv;
            if (sraw[1] >= 0) out[LOGITS_SZ + sraw[1]] = p1 + bcv;
        }
    }
}

extern "C" void kernel_launch(void* const* d_in, const int* in_sizes, int n_in,
                              void* d_out, int out_size, void* d_ws, size_t ws_size,
                              hipStream_t stream) {
    const float* obs  = (const float*)d_in[0];
    const int*   pick = (const int*)d_in[1];
    const int*   htyp = (const int*)d_in[2];
    const int*   gp   = (const int*)d_in[3];
    const float* W1   = (const float*)d_in[4];
    const float* b1   = (const float*)d_in[5];
    const float* W2   = (const float*)d_in[6];
    const float* b2   = (const float*)d_in[7];
    const float* Wc1  = (const float*)d_in[8];
    const float* bc1  = (const float*)d_in[9];
    const float* Wc2  = (const float*)d_in[10];
    const float* bc2  = (const float*)d_in[11];
    float* out = (float*)d_out;

    int*    counts = (int*)d_ws;              // 160 ints (padded, e -> counts[e*16])
    int*    order  = counts + 160;            // E_EXP * CAP ints (-1 sentinel)
    ushort* W1p    = (ushort*)(order + E_EXP * CAP);
    ushort* W2p    = W1p + W1P_N;
    ushort* Wc1p   = W2p + W2P_N;

    hipMemsetAsync(counts, 0, 160 * sizeof(int), stream);
    hipMemsetAsync(order, 0xFF, E_EXP * CAP * sizeof(int), stream);
    prep_bucket_kernel<<<PB_BLOCKS, 256, 0, stream>>>(
        W1, W2, Wc1, b1, bc1, pick, counts, order, W1p, W2p, Wc1p);
    moe_kernel<<<E_EXP * MAXC, 512, 0, stream>>>(
        obs, htyp, gp, b2, bc2, order,
        W1p, W2p, Wc1p, Wc2, out);
}

// Round 7
// 137.199 us; speedup vs baseline: 1.2631x; 1.2306x over previous
//
#include <hip/hip_runtime.h>
#include <hip/hip_bf16.h>

// ---- problem constants ----
#define T_DIM   2048
#define A_DIM   64
#define N_TOK   (T_DIM * A_DIM)     // 131072
#define RAWOB   120
#define N_TP    5
#define E_EXP   10
#define D_DIM   126                  // RAWOB + N_TP + 1
#define DP      128                  // padded K (row 126 = bias, row 127 = 0)
#define H_DIM   128
#define N_ACT   16
#define BTOK    256                  // contiguous tokens per block
#define NBLK    (N_TOK / BTOK)       // 512 blocks
#define LOGITS_SZ (N_TOK * N_ACT)    // 2097152

typedef __bf16 bh8 __attribute__((ext_vector_type(8)));
typedef ushort u16x8 __attribute__((ext_vector_type(8)));
typedef ushort u16x4 __attribute__((ext_vector_type(4)));
typedef short  s16x4 __attribute__((ext_vector_type(4)));
typedef float  f32x4 __attribute__((ext_vector_type(4)));

__device__ __forceinline__ f32x4 mfma16(bh8 a, bh8 b, f32x4 c) {
    return __builtin_amdgcn_mfma_f32_16x16x32_bf16(a, b, c, 0, 0, 0);
}
// K=16 variant: per-lane k-quads (k = 4*lq + j) — matches swapped-L1 output layout
__device__ __forceinline__ f32x4 mfma16k16(s16x4 a, s16x4 b, f32x4 c) {
    return __builtin_amdgcn_mfma_f32_16x16x16bf16_1k(a, b, c, 0, 0, 0);
}

__device__ __forceinline__ ushort f2bf(float f) {
    unsigned x = __builtin_bit_cast(unsigned, f);
    unsigned r = (x + 0x7fffu + ((x >> 16) & 1u)) >> 16;   // round-nearest-even
    return (ushort)r;
}

#define W1P_N (E_EXP * H_DIM * DP)           // 163840 ushorts
#define W2P_N (E_EXP * N_ACT * H_DIM)        // 20480
#define WC1P_N (DP * DP)                     // 16384

// ---------------- kernel 0: weight packing only ----------------
// blocks 0..43:   W1/Wc1 packing (bias folded into padded row 126)
// blocks 44..123: W2 packing (16x16x16 B-frag layout)
#define PB_BLOCKS 124

__global__ __launch_bounds__(256) void prep_kernel(
    const float* __restrict__ W1, const float* __restrict__ W2,
    const float* __restrict__ Wc1, const float* __restrict__ b1,
    const float* __restrict__ bc1,
    ushort* __restrict__ W1p, ushort* __restrict__ W2p, ushort* __restrict__ Wc1p)
{
    int bx = blockIdx.x, tid = threadIdx.x;
    if (bx < 44) {
        __shared__ ushort st[32][130];   // 32 d-rows x 128 n, padded
        const float* src;
        const float* bias;
        ushort* dstbase;
        int kt;
        if (bx < 40) {                   // W1: e = bx>>2, kt = bx&3
            int e = bx >> 2;
            kt = bx & 3;
            src = W1 + (e * D_DIM + kt * 32) * H_DIM;
            bias = b1 + e * H_DIM;
            dstbase = W1p + e * (H_DIM * DP);
        } else {                         // Wc1: kt = bx-40
            kt = bx - 40;
            src = Wc1 + kt * 32 * H_DIM;
            bias = bc1;
            dstbase = Wc1p;
        }
        int dmax = D_DIM - kt * 32;      // 32,32,32,30
#pragma unroll
        for (int p = 0; p < 16; ++p) {
            int idx = p * 256 + tid;
            int dd = idx >> 7, n = idx & 127;
            float v;
            if (dd < dmax)                    v = src[dd * H_DIM + n];   // coalesced in n
            else if (kt == 3 && dd == 30)     v = bias[n];               // bias row (k=126)
            else                              v = 0.f;                   // k=127 pad
            st[dd][n] = f2bf(v);
        }
        __syncthreads();
#pragma unroll
        for (int p = 0; p < 16; ++p) {
            int idx = p * 256 + tid;
            int dd = idx >> 7, n = idx & 127;
            // frag position: nt=n>>4, lm=n&15, lq=dd>>3, j=dd&7
            dstbase[((n >> 4) * 4 + kt) * 512 + ((dd >> 3) * 16 + (n & 15)) * 8 + (dd & 7)]
                = st[dd][n];
        }
    } else {
        // W2 packed as 16x16x16 B-frags: tile kk (k = kk*16 + 4*lq + j), col = lm
        int i = (bx - 44) * 256 + tid;   // [0, 20480)
        int e   = i >> 11;
        int rem = i & 2047;
        int kk  = rem >> 8;
        int idx = rem & 255;
        int l = idx >> 2, j = idx & 3;
        int lq = l >> 4, lm = l & 15;
        W2p[i] = f2bf(W2[(e * H_DIM + kk * 16 + lq * 4 + j) * N_ACT + lm]);
    }
}

// ---------------- kernel 1: natural-order fused MoE + critic ------------------
// Each block owns 256 CONTIGUOUS tokens: obs read fully coalesced -> LDS (bf16,
// granule-XOR-swizzled). Local bucket via LDS atomics -> per-expert 16-row MFMA
// tiles whose A-rows gather from LDS (cheap) instead of HBM (the old 40us wall).
// Expert weights stream per-tile from L2 (W1p 320KB chip-hot). No order array,
// no global bucketing, no memsets, no scattered HBM access anywhere.
__global__ __launch_bounds__(512, 4) void moe_kernel(
    const float* __restrict__ obs, const int* __restrict__ pick,
    const int* __restrict__ hete_type, const int* __restrict__ gp_sel,
    const float* __restrict__ b2, const float* __restrict__ bc2,
    const ushort* __restrict__ W1p, const ushort* __restrict__ W2p,
    const ushort* __restrict__ Wc1p, const float* __restrict__ Wc2,
    float* __restrict__ out)
{
    __shared__ __align__(16) ushort xa[BTOK * 128];   // 64KB swizzled bf16 rows
    __shared__ short map[416];                        // padded slot -> local token
    __shared__ short texp[32];                        // tile -> expert
    __shared__ int lc[16], lbase[16];
    __shared__ int nt_tot;

    const int bx  = blockIdx.x;
    const int tid = threadIdx.x;
    const int gbase = bx * BTOK;

    if (tid < 16) lc[tid] = 0;
    for (int i = tid; i < 416; i += 512) map[i] = -1;
    __syncthreads();

    // ---- local bucket count (threads 0..255, one token each) ----
    int mye = 0, myloc = 0;
    if (tid < 256) {
        mye = pick[gbase + tid];
        myloc = atomicAdd(&lc[mye], 1);
    }

    // ---- stage obs -> LDS bf16, granule-swizzled; fully coalesced global ----
    // idx in [0,3840): row r = idx/15, granule g = idx%15 (8 floats -> 16B bf16)
#pragma unroll
    for (int p = 0; p < 8; ++p) {
        int idx = p * 512 + tid;
        if (idx < 3840) {
            int r = idx / 15, g = idx - r * 15;
            const float* s = obs + (size_t)(gbase + r) * RAWOB + g * 8;
            float4 u0 = *(const float4*)(const void*)s;
            float4 u1 = *(const float4*)(const void*)(s + 4);
            u16x8 t;
            t[0] = f2bf(u0.x); t[1] = f2bf(u0.y); t[2] = f2bf(u0.z); t[3] = f2bf(u0.w);
            t[4] = f2bf(u1.x); t[5] = f2bf(u1.y); t[6] = f2bf(u1.z); t[7] = f2bf(u1.w);
            *(u16x8*)(void*)(xa + r * 128 + (g ^ (r & 15)) * 8) = t;
        }
    }
    // augment granule 15: [hete_type, gp_obs(5), 1.0 (bias k=126), 0]
    if (tid < 256) {
        int tok = gbase + tid;
        int ht = hete_type[tok];
        int tt = tok >> 6;                  // token / A_DIM
        u16x8 t;
        t[0] = f2bf((float)ht);
#pragma unroll
        for (int q = 0; q < N_TP; ++q) {
            float g = (q == ht) ? -1.0f : (float)gp_sel[tt * N_TP + q];
            t[1 + q] = f2bf(g);
        }
        t[6] = (ushort)0x3F80;              // 1.0 -> picks up bias row 126
        t[7] = 0;
        *(u16x8*)(void*)(xa + tid * 128 + (15 ^ (tid & 15)) * 8) = t;
    }
    __syncthreads();

    // ---- serial tile layout (10 experts; trivial) ----
    if (tid == 0) {
        int pb = 0, t = 0;
#pragma unroll
        for (int e = 0; e < E_EXP; ++e) {
            lbase[e] = pb;
            int nt = (lc[e] + 15) >> 4;
            for (int k = 0; k < nt; ++k) texp[t++] = (short)e;
            pb += nt << 4;
        }
        nt_tot = t;
    }
    __syncthreads();
    if (tid < 256) map[lbase[mye] + myloc] = (short)tid;
    __syncthreads();

    const int w = tid >> 6;
    const int l = tid & 63;
    const int lm = l & 15;
    const int lq = l >> 4;
    const float bcv = bc2[0];

    // ---- expert path: waves grab tiles round-robin; weights from L2 ----
    const int NT = nt_tot;
    for (int i = w; i < NT; i += 8) {
        const int e  = texp[i];
        const int tb = i << 4;
        const int mlt = map[tb + lm];
        const int row = mlt < 0 ? 0 : mlt;
        bh8 a[4];
#pragma unroll
        for (int kt = 0; kt < 4; ++kt) {
            int g = kt * 4 + lq;
            a[kt] = *(const bh8*)(const void*)(xa + row * 128 + (g ^ (row & 15)) * 8);
        }
        const ushort* w1e = W1p + e * (H_DIM * DP);
        const ushort* w2e = W2p + e * 2048;
        const float bb = b2[e * N_ACT + lm];
        f32x4 y = (f32x4){0.f, 0.f, 0.f, 0.f};
#pragma unroll
        for (int nt = 0; nt < 8; ++nt) {
            f32x4 ae = (f32x4){0.f, 0.f, 0.f, 0.f};
#pragma unroll
            for (int kt = 0; kt < 4; ++kt) {
                bh8 wf = *(const bh8*)(const void*)(w1e + (nt * 4 + kt) * 512 + l * 8);
                ae = mfma16(wf, a[kt], ae);             // swapped operands: h^T in regs
            }
            u16x4 hp;
#pragma unroll
            for (int r = 0; r < 4; ++r) hp[r] = f2bf(fmaxf(ae[r], 0.f));
            s16x4 w2f = *(const s16x4*)(const void*)(w2e + nt * 256 + l * 4);
            y = mfma16k16(__builtin_bit_cast(s16x4, hp), w2f, y);
        }
#pragma unroll
        for (int r = 0; r < 4; ++r) {
            int m2 = map[tb + lq * 4 + r];
            if (m2 >= 0) out[(size_t)(gbase + m2) * N_ACT + lm] = y[r] + bb;
        }
    }

    // ---- critic: natural-order rows (perfect swizzle pattern), Wc1 from L2 ----
    {
        const int r0 = w * 32;
        const int row0 = r0 + lm, row1 = r0 + 16 + lm;
        bh8 a0[4], a1[4];
#pragma unroll
        for (int kt = 0; kt < 4; ++kt) {
            int g = kt * 4 + lq;
            a0[kt] = *(const bh8*)(const void*)(xa + row0 * 128 + (g ^ (row0 & 15)) * 8);
            a1[kt] = *(const bh8*)(const void*)(xa + row1 * 128 + (g ^ (row1 & 15)) * 8);
        }
        float p0 = 0.f, p1 = 0.f;
#pragma unroll
        for (int nt = 0; nt < 8; ++nt) {
            f32x4 c0 = (f32x4){0.f,0.f,0.f,0.f}, c1 = c0;
#pragma unroll
            for (int kt = 0; kt < 4; ++kt) {
                bh8 wf = *(const bh8*)(const void*)(Wc1p + (nt * 4 + kt) * 512 + l * 8);
                c0 = mfma16(wf, a0[kt], c0);
                c1 = mfma16(wf, a1[kt], c1);
            }
            const float4 wc = *(const float4*)(const void*)(Wc2 + nt * 16 + lq * 4);
            p0 += fmaxf(c0[0], 0.f) * wc.x + fmaxf(c0[1], 0.f) * wc.y
                + fmaxf(c0[2], 0.f) * wc.z + fmaxf(c0[3], 0.f) * wc.w;
            p1 += fmaxf(c1[0], 0.f) * wc.x + fmaxf(c1[1], 0.f) * wc.y
                + fmaxf(c1[2], 0.f) * wc.z + fmaxf(c1[3], 0.f) * wc.w;
        }
        // lane (lq,lm) holds token's partial over its n-subset; sum over lq
        p0 += __shfl_xor(p0, 16, 64); p0 += __shfl_xor(p0, 32, 64);
        p1 += __shfl_xor(p1, 16, 64); p1 += __shfl_xor(p1, 32, 64);
        if (lq == 0) {
            out[LOGITS_SZ + gbase + row0] = p0 + bcv;
            out[LOGITS_SZ + gbase + row1] = p1 + bcv;
        }
    }
}

extern "C" void kernel_launch(void* const* d_in, const int* in_sizes, int n_in,
                              void* d_out, int out_size, void* d_ws, size_t ws_size,
                              hipStream_t stream) {
    const float* obs  = (const float*)d_in[0];
    const int*   pick = (const int*)d_in[1];
    const int*   htyp = (const int*)d_in[2];
    const int*   gp   = (const int*)d_in[3];
    const float* W1   = (const float*)d_in[4];
    const float* b1   = (const float*)d_in[5];
    const float* W2   = (const float*)d_in[6];
    const float* b2   = (const float*)d_in[7];
    const float* Wc1  = (const float*)d_in[8];
    const float* bc1  = (const float*)d_in[9];
    const float* Wc2  = (const float*)d_in[10];
    const float* bc2  = (const float*)d_in[11];
    float* out = (float*)d_out;

    ushort* W1p  = (ushort*)d_ws;
    ushort* W2p  = W1p + W1P_N;
    ushort* Wc1p = W2p + W2P_N;

    prep_kernel<<<PB_BLOCKS, 256, 0, stream>>>(
        W1, W2, Wc1, b1, bc1, W1p, W2p, Wc1p);
    moe_kernel<<<NBLK, 512, 0, stream>>>(
        obs, pick, htyp, gp, b2, bc2,
        W1p, W2p, Wc1p, Wc2, out);
}